// Round 18
// baseline (170.028 us; speedup 1.0000x reference)
//
#include <hip/hip_runtime.h>

typedef __attribute__((ext_vector_type(8))) __bf16 bf16x8;
typedef __attribute__((ext_vector_type(2))) __bf16 bf16x2;
typedef __attribute__((ext_vector_type(8))) unsigned short u16x8;
typedef __attribute__((ext_vector_type(4))) float f32x4;
typedef __attribute__((ext_vector_type(16))) float f32x16;
typedef __attribute__((ext_vector_type(2))) unsigned int u32x2;
typedef __attribute__((ext_vector_type(4))) unsigned int u32x4;
typedef unsigned short u16;
typedef unsigned int u32;

constexpr int Bb = 4, Ss = 2048, Ee = 1024, Hh = 16, HDd = 64;
constexpr int Mm = Bb * Ss;   // 8192
constexpr int N3 = 3 * Ee;    // 3072
constexpr float QSC = 0.18033688011112042f;  // 0.125 * log2(e)
constexpr int BHSTRIDE = Ss * HDd;            // 131072 u16 per (b,h) slice
constexpr float M0 = 8.0f;                    // static softmax base (exp2 units)

__device__ __forceinline__ u16 f2bf(float f) {
  u32 u = __builtin_bit_cast(u32, f);
  u = (u + 0x7FFFu + ((u >> 16) & 1u)) >> 16;
  return (u16)u;
}
__device__ __forceinline__ u32 pk2(float a, float b) {
  bf16x2 t;
  t[0] = (__bf16)a;
  t[1] = (__bf16)b;
  return __builtin_bit_cast(u32, t);
}
// raw v_exp_f32 (no denormal-fixup sequence); inputs are <= 0, -inf -> 0
__device__ __forceinline__ float ex2(float x) {
#if __has_builtin(__builtin_amdgcn_exp2f)
  return __builtin_amdgcn_exp2f(x);
#else
  float r;
  asm volatile("v_exp_f32 %0, %1" : "=v"(r) : "v"(x));
  return r;
#endif
}

__device__ __forceinline__ void gload_lds16(const void* g, void* l) {
  __builtin_amdgcn_global_load_lds(
      (__attribute__((address_space(1))) void*)g,
      (__attribute__((address_space(3))) void*)l, 16, 0, 0);
}

__device__ __forceinline__ f32x4 mfma16(bf16x8 a, bf16x8 b, f32x4 c) {
  return __builtin_amdgcn_mfma_f32_16x16x32_bf16(a, b, c, 0, 0, 0);
}
__device__ __forceinline__ f32x16 mfma32(bf16x8 a, bf16x8 b, f32x16 c) {
  return __builtin_amdgcn_mfma_f32_32x32x16_bf16(a, b, c, 0, 0, 0);
}

// ---------------- cast fp32 -> bf16 ----------------
__global__ void cast_x_kernel(const float* __restrict__ x, u16* __restrict__ xb, int n4) {
  int i = blockIdx.x * blockDim.x + threadIdx.x;
  int stride = gridDim.x * blockDim.x;
  for (; i < n4; i += stride) {
    float4 v = reinterpret_cast<const float4*>(x)[i];
    ushort4 o;
    o.x = f2bf(v.x); o.y = f2bf(v.y); o.z = f2bf(v.z); o.w = f2bf(v.w);
    reinterpret_cast<ushort4*>(xb)[i] = o;
  }
}

// ---------------- transpose-cast weight [K][N] fp32 -> [N][K] bf16 ----------------
__global__ void transpose_cast_kernel(const float* __restrict__ W, u16* __restrict__ Wt,
                                      int K, int N) {
  __shared__ float tile[32][33];
  int n0 = blockIdx.x * 32, k0 = blockIdx.y * 32;
  int tx = threadIdx.x & 31, ty = threadIdx.x >> 5;
#pragma unroll
  for (int i = 0; i < 4; ++i)
    tile[ty + i * 8][tx] = W[(size_t)(k0 + ty + i * 8) * N + n0 + tx];
  __syncthreads();
#pragma unroll
  for (int i = 0; i < 4; ++i)
    Wt[(size_t)(n0 + ty + i * 8) * K + k0 + tx] = f2bf(tile[tx][ty + i * 8]);
}

// ---------------- GEMM1: 256x256, BK=64, 8 waves, 2-buf LDS (128 KB) --------
// All 8 next-tile stages issued at tile top (issue-to-wait = one full tile,
// so the tile-top vmcnt(0) drain is cheap); one barrier per tile; conflict-free
// mfma16 LDS read pattern; R10-verified fragment-pack epilogue.
__global__ __launch_bounds__(512, 1) void gemm256_qkv(
    const u16* __restrict__ A, const u16* __restrict__ Bt,
    const float* __restrict__ bias,
    u16* __restrict__ Qr, u16* __restrict__ Kp, u16* __restrict__ Vp) {
  extern __shared__ __attribute__((aligned(16))) u16 dyn[];
  constexpr int K = 1024, NT = 16;

  int f = blockIdx.x;
  int swz = (f & 7) * 48 + (f >> 3);  // XCD swizzle (384 % 8 == 0)
  int bx = swz % 12, by = swz / 12;
  int m0 = by * 256, n0 = bx * 256;

  int tid = threadIdx.x, lane = tid & 63, wid = tid >> 6;
  int wr = wid >> 2, wc = wid & 3;  // wave grid 2(M) x 4(N): 128x64 per wave
  int l7 = lane & 7, l8 = lane >> 3;
  int swcol = (l7 ^ l8) * 8;  // inverse-swizzled source chunk

  const u16* Ab = A + (size_t)(m0 + l8) * K + swcol;
  const u16* Bb = Bt + (size_t)(n0 + l8) * K + swcol;

  f32x4 acc[8][4];
  const f32x4 fz = {0.f, 0.f, 0.f, 0.f};
#pragma unroll
  for (int mi = 0; mi < 8; ++mi)
#pragma unroll
    for (int nj = 0; nj < 4; ++nj) acc[mi][nj] = fz;

  // 32 chunks each (8 rows x 64 cols = 1KB); wave stages chunks wid*4+{0..3}
  auto STA = [&](int tt, int c) {
    int ch = wid * 4 + c;
    gload_lds16(Ab + (size_t)(ch * 8) * K + tt * 64,
                dyn + (tt & 1) * 16384 + ch * 512);
  };
  auto STB = [&](int tt, int c) {
    int ch = wid * 4 + c;
    gload_lds16(Bb + (size_t)(ch * 8) * K + tt * 64,
                dyn + 32768 + (tt & 1) * 16384 + ch * 512);
  };
  auto LDA = [&](const u16* buf, int mi, int ks) -> bf16x8 {
    int row = wr * 128 + mi * 16 + (lane & 15);
    int j = ((ks * 4 + (lane >> 4)) ^ l7) * 8;
    return *(const bf16x8*)&buf[row * 64 + j];
  };
  auto LDB = [&](const u16* buf, int ni, int ks) -> bf16x8 {
    int row = wc * 64 + ni * 16 + (lane & 15);
    int j = ((ks * 4 + (lane >> 4)) ^ l7) * 8;
    return *(const bf16x8*)&buf[row * 64 + j];
  };

  // prologue: stage tile 0
#pragma unroll
  for (int c = 0; c < 4; ++c) STA(0, c);
#pragma unroll
  for (int c = 0; c < 4; ++c) STB(0, c);

  for (int t = 0; t < NT; ++t) {
    const u16* Ar = dyn + (t & 1) * 16384;
    const u16* Br = dyn + 32768 + (t & 1) * 16384;
    asm volatile("s_waitcnt vmcnt(0)" ::: "memory");
    __builtin_amdgcn_sched_barrier(0);
    __builtin_amdgcn_s_barrier();
    __builtin_amdgcn_sched_barrier(0);
    if (t + 1 < NT) {
#pragma unroll
      for (int c = 0; c < 4; ++c) STA(t + 1, c);
#pragma unroll
      for (int c = 0; c < 4; ++c) STB(t + 1, c);
    }
#pragma unroll
    for (int kk = 0; kk < 2; ++kk) {
      bf16x8 bfr[4];
#pragma unroll
      for (int ni = 0; ni < 4; ++ni) bfr[ni] = LDB(Br, ni, kk);
#pragma unroll
      for (int mi = 0; mi < 8; ++mi) {
        bf16x8 af = LDA(Ar, mi, kk);
        __builtin_amdgcn_s_setprio(1);
#pragma unroll
        for (int ni = 0; ni < 4; ++ni)
          acc[mi][ni] = mfma16(af, bfr[ni], acc[mi][ni]);
        __builtin_amdgcn_s_setprio(0);
      }
      asm volatile("" ::: "memory");
    }
  }
  __syncthreads();

  // ---- epilogue: 2 passes x 2 col-groups through reused LDS (stride 72) ----
  int gi0 = bx * 4;
  int bb = m0 >> 11;
  int mrow0 = m0 & 2047;
#pragma unroll
  for (int p = 0; p < 2; ++p) {
    if ((wc >> 1) == p) {
      int gg = wc & 1;
      int gi = gi0 + p * 2 + gg;
      int typ = gi % 3;
      float cs = (typ == 0) ? QSC : 1.0f;
#pragma unroll
      for (int nj = 0; nj < 4; ++nj) {
        int dl = nj * 16 + (lane & 15);
        float bn = bias[gi * 64 + dl];
#pragma unroll
        for (int mi = 0; mi < 8; ++mi)
#pragma unroll
          for (int r = 0; r < 4; ++r) {
            int row = wr * 128 + mi * 16 + (lane >> 4) * 4 + r;
            dyn[(gg * 256 + row) * 72 + dl] = f2bf((acc[mi][nj][r] + bn) * cs);
          }
      }
    }
    __syncthreads();
#pragma unroll
    for (int gg = 0; gg < 2; ++gg) {
      int gi = gi0 + p * 2 + gg;
      int typ = gi % 3, h = gi / 3;
      size_t basebh = (size_t)(bb * 16 + h) * BHSTRIDE;
      if (typ == 2) {
#pragma unroll
        for (int i = 0; i < 4; ++i) {
          int c = tid + 512 * i;
          int dl = c & 63, tsel = (c >> 6) & 3, kv8 = c >> 8;
          u16x8 val;
          int lrow = gg * 256 + tsel * 64 + kv8 * 8;
#pragma unroll
          for (int e = 0; e < 8; ++e) val[e] = dyn[(lrow + e) * 72 + dl];
          int tile = (mrow0 >> 6) + tsel;
          size_t o = basebh + (size_t)tile * 4096 + (dl >> 5) * 2048 +
                     (kv8 >> 1) * 512 + (kv8 & 1) * 256 + (dl & 31) * 8;
          *(u16x8*)(Vp + o) = val;
        }
      } else {
#pragma unroll
        for (int i = 0; i < 4; ++i) {
          int c = tid + 512 * i;
          int sl = c >> 3, dc = c & 7;
          u16x8 val = *(const u16x8*)&dyn[(gg * 256 + sl) * 72 + dc * 8];
          int srw = mrow0 + sl;
          if (typ == 0) {
            *(u16x8*)(Qr + basebh + (size_t)srw * 64 + dc * 8) = val;
          } else {
            int tile = srw >> 6, rl = srw & 63;
            size_t o = basebh + (size_t)tile * 4096 + (rl >> 5) * 2048 +
                       (dc >> 1) * 512 + (dc & 1) * 256 + (rl & 31) * 8;
            *(u16x8*)(Kp + o) = val;
          }
        }
      }
    }
    __syncthreads();
  }
}

// ---------------- GEMM2: 128x256, BK=64, 8 waves, 3-buf, counted vmcnt ------
// (R11-proven structure, fp32 out)
__global__ __launch_bounds__(512, 1) void gemm_proj(
    const u16* __restrict__ A, const u16* __restrict__ Bt,
    const float* __restrict__ bias, int xtiles, int cpx,
    float* __restrict__ Cout) {
  extern __shared__ __attribute__((aligned(16))) u16 dyn[];
  constexpr int K = 1024, NT = 16;
  constexpr int BUFSTRIDE = 24576;  // u16: 48KB per buffer

  int f = blockIdx.x;
  int swz = (f & 7) * cpx + (f >> 3);
  int bx = swz % xtiles, by = swz / xtiles;
  int m0 = by * 128, n0 = bx * 256;

  int tid = threadIdx.x, lane = tid & 63, wid = tid >> 6;
  int wr = wid >> 2, wc = wid & 3;
  int l7 = lane & 7, l8 = lane >> 3;
  int swcol = (l7 ^ l8) * 8;

  const u16* Ab = A + (size_t)(m0 + l8) * K + swcol;
  const u16* Bb = Bt + (size_t)(n0 + l8) * K + swcol;

  f32x4 acc[4][4];
  const f32x4 fz = {0.f, 0.f, 0.f, 0.f};
#pragma unroll
  for (int mi = 0; mi < 4; ++mi)
#pragma unroll
    for (int nj = 0; nj < 4; ++nj) acc[mi][nj] = fz;

  auto STA = [&](int tt, int c) {
    int ch = wid * 2 + c;
    gload_lds16(Ab + (size_t)(ch * 8) * K + tt * 64,
                dyn + (tt % 3) * BUFSTRIDE + ch * 512);
  };
  auto STB = [&](int tt, int c) {
    int ch = wid * 4 + c;
    gload_lds16(Bb + (size_t)(ch * 8) * K + tt * 64,
                dyn + (tt % 3) * BUFSTRIDE + 8192 + ch * 512);
  };
  auto LDA = [&](const u16* buf, int mi, int ks) -> bf16x8 {
    int row = wr * 64 + mi * 16 + (lane & 15);
    int j = ((ks * 4 + (lane >> 4)) ^ l7) * 8;
    return *(const bf16x8*)&buf[row * 64 + j];
  };
  auto LDB = [&](const u16* buf, int ni, int ks) -> bf16x8 {
    int row = wc * 64 + ni * 16 + (lane & 15);
    int j = ((ks * 4 + (lane >> 4)) ^ l7) * 8;
    return *(const bf16x8*)&buf[row * 64 + j];
  };

#pragma unroll
  for (int c = 0; c < 2; ++c) STA(0, c);
#pragma unroll
  for (int c = 0; c < 4; ++c) STB(0, c);
#pragma unroll
  for (int c = 0; c < 2; ++c) STA(1, c);
#pragma unroll
  for (int c = 0; c < 4; ++c) STB(1, c);

  for (int t = 0; t < NT; ++t) {
    const u16* Ar = dyn + (t % 3) * BUFSTRIDE;
    const u16* Br = Ar + 8192;
    if (t + 1 < NT)
      asm volatile("s_waitcnt vmcnt(6)" ::: "memory");
    else
      asm volatile("s_waitcnt vmcnt(0)" ::: "memory");
    __builtin_amdgcn_sched_barrier(0);
    __builtin_amdgcn_s_barrier();
    __builtin_amdgcn_sched_barrier(0);

    bool pre2 = (t + 2) < NT;
#pragma unroll
    for (int kk = 0; kk < 2; ++kk) {
      bf16x8 af[4], bfr[4];
#pragma unroll
      for (int mi = 0; mi < 4; ++mi) af[mi] = LDA(Ar, mi, kk);
#pragma unroll
      for (int ni = 0; ni < 4; ++ni) bfr[ni] = LDB(Br, ni, kk);
      if (kk == 0 && pre2) { STA(t + 2, 0); STA(t + 2, 1); }
      if (kk == 1 && pre2) { STB(t + 2, 0); STB(t + 2, 1); STB(t + 2, 2); STB(t + 2, 3); }
      __builtin_amdgcn_s_setprio(1);
#pragma unroll
      for (int mi = 0; mi < 4; ++mi)
#pragma unroll
        for (int ni = 0; ni < 4; ++ni)
          acc[mi][ni] = mfma16(af[mi], bfr[ni], acc[mi][ni]);
      __builtin_amdgcn_s_setprio(0);
      asm volatile("" ::: "memory");
    }
  }
  __syncthreads();

  int Nn = xtiles * 256;
#pragma unroll
  for (int nj = 0; nj < 4; ++nj) {
    int n = n0 + wc * 64 + nj * 16 + (lane & 15);
    float bn = bias[n];
#pragma unroll
    for (int mi = 0; mi < 4; ++mi)
#pragma unroll
      for (int r = 0; r < 4; ++r) {
        int m = m0 + wr * 64 + mi * 16 + (lane >> 4) * 4 + r;
        Cout[(size_t)m * Nn + n] = acc[mi][nj][r] + bn;
      }
  }
}

// ---------------- causal flash attention: 4-wave KV-split, static base ------
// (exact R15 kernel: raw exp2, -M0 in accumulator, permlane exchange)
__global__ __launch_bounds__(256) void attn_kernel(const u16* __restrict__ Qr,
                                                   const u16* __restrict__ Kp,
                                                   const u16* __restrict__ Vp,
                                                   u16* __restrict__ aout) {
  __shared__ float mbuf[2][64][33];  // [slot][lane][{l, o[32]}]

  int bh = blockIdx.x;
  int j = gridDim.y - 1 - blockIdx.y;  // q-block 0..63, big-first
  int tid = threadIdx.x, w = tid >> 6, lane = tid & 63;
  int hi = lane >> 5, ln31 = lane & 31;
  int qrow = 32 * j + ln31;
  int nt = (j >> 1) + 1;
  int par = (j & 1) ? 32 : 0;

  size_t basebh = (size_t)bh * BHSTRIDE;
  const u16* kpb = Kp + basebh + hi * 256 + ln31 * 8;
  const u16* vpb = Vp + basebh + hi * 256 + ln31 * 8;

  bf16x8 qf[4];
#pragma unroll
  for (int kc = 0; kc < 4; ++kc)
    qf[kc] = *(const bf16x8*)(Qr + basebh + (size_t)qrow * 64 + kc * 16 + hi * 8);

  f32x16 o[2];
#pragma unroll
  for (int dm = 0; dm < 2; ++dm)
#pragma unroll
    for (int e = 0; e < 16; ++e) o[dm][e] = 0.f;
  float lrun = 0.f;

  for (int t = w; t < nt; t += 4) {
    const u16* kpt = kpb + (size_t)t * 4096;
    const u16* vpt = vpb + (size_t)t * 4096;
    bf16x8 kf[2][4], vf[2][4];
#pragma unroll
    for (int mt = 0; mt < 2; ++mt)
#pragma unroll
      for (int kc = 0; kc < 4; ++kc)
        kf[mt][kc] = *(const bf16x8*)(kpt + mt * 2048 + kc * 512);
#pragma unroll
    for (int dm = 0; dm < 2; ++dm)
#pragma unroll
      for (int kw = 0; kw < 4; ++kw)
        vf[dm][kw] = *(const bf16x8*)(vpt + dm * 2048 + kw * 512);

    f32x16 sc[2];
#pragma unroll
    for (int mt = 0; mt < 2; ++mt)
#pragma unroll
      for (int e = 0; e < 16; ++e) sc[mt][e] = -M0;
    __builtin_amdgcn_s_setprio(1);
#pragma unroll
    for (int mt = 0; mt < 2; ++mt)
#pragma unroll
      for (int kc = 0; kc < 4; ++kc)
        sc[mt] = mfma32(kf[mt][kc], qf[kc], sc[mt]);
    __builtin_amdgcn_s_setprio(0);

    if (t == nt - 1) {
#pragma unroll
      for (int mt = 0; mt < 2; ++mt)
#pragma unroll
        for (int r = 0; r < 16; ++r) {
          bool msk = (32 * mt + (r & 3) + 8 * (r >> 2) + 4 * hi) > (ln31 + par);
          sc[mt][r] = msk ? -__builtin_inff() : sc[mt][r];
        }
    }
    float s0a = 0.f, s1a = 0.f, s2a = 0.f, s3a = 0.f;
#pragma unroll
    for (int mt = 0; mt < 2; ++mt)
#pragma unroll
      for (int r = 0; r < 16; ++r) {
        float e = ex2(sc[mt][r]);
        sc[mt][r] = e;
        if ((r & 3) == 0) s0a += e;
        else if ((r & 3) == 1) s1a += e;
        else if ((r & 3) == 2) s2a += e;
        else s3a += e;
      }
    float sum = (s0a + s1a) + (s2a + s3a);
    sum += __shfl_xor(sum, 32);
    lrun += sum;

#pragma unroll
    for (int kw = 0; kw < 4; ++kw) {
      int mt = kw >> 1, k8 = (kw & 1) * 8;
      u32 a0 = pk2(sc[mt][k8 + 0], sc[mt][k8 + 1]);
      u32 a1 = pk2(sc[mt][k8 + 2], sc[mt][k8 + 3]);
      u32 b0 = pk2(sc[mt][k8 + 4], sc[mt][k8 + 5]);
      u32 b1 = pk2(sc[mt][k8 + 6], sc[mt][k8 + 7]);
      u32x2 r0 = __builtin_amdgcn_permlane32_swap(a0, b0, false, false);
      u32x2 r1 = __builtin_amdgcn_permlane32_swap(a1, b1, false, false);
      u32x4 fw;
      fw.x = r0.x;
      fw.y = r1.x;
      fw.z = r0.y;
      fw.w = r1.y;
      bf16x8 pf = __builtin_bit_cast(bf16x8, fw);
      __builtin_amdgcn_s_setprio(1);
#pragma unroll
      for (int dm = 0; dm < 2; ++dm)
        o[dm] = mfma32(vf[dm][kw], pf, o[dm]);  // O^T[d][q]
      __builtin_amdgcn_s_setprio(0);
    }
  }

  // ---- merge partials: plain sums (same static base) ----
  if (w >= 2) {
    mbuf[w - 2][lane][0] = lrun;
#pragma unroll
    for (int dm = 0; dm < 2; ++dm)
#pragma unroll
      for (int e = 0; e < 16; ++e) mbuf[w - 2][lane][1 + dm * 16 + e] = o[dm][e];
  }
  __syncthreads();
  if (w < 2) {
    lrun += mbuf[w][lane][0];
#pragma unroll
    for (int dm = 0; dm < 2; ++dm)
#pragma unroll
      for (int e = 0; e < 16; ++e) o[dm][e] += mbuf[w][lane][1 + dm * 16 + e];
  }
  __syncthreads();
  if (w == 1) {
    mbuf[0][lane][0] = lrun;
#pragma unroll
    for (int dm = 0; dm < 2; ++dm)
#pragma unroll
      for (int e = 0; e < 16; ++e) mbuf[0][lane][1 + dm * 16 + e] = o[dm][e];
  }
  __syncthreads();
  if (w == 0) {
    lrun += mbuf[0][lane][0];
#pragma unroll
    for (int dm = 0; dm < 2; ++dm)
#pragma unroll
      for (int e = 0; e < 16; ++e) o[dm][e] += mbuf[0][lane][1 + dm * 16 + e];
    int b = bh >> 4, h = bh & 15;
    float inv = 1.f / lrun;
    u16* orow = aout + (size_t)(b * Ss + qrow) * Ee + h * HDd;
#pragma unroll
    for (int dm = 0; dm < 2; ++dm)
#pragma unroll
      for (int g = 0; g < 4; ++g) {
        ushort4 st;
        st.x = f2bf(o[dm][4 * g + 0] * inv);
        st.y = f2bf(o[dm][4 * g + 1] * inv);
        st.z = f2bf(o[dm][4 * g + 2] * inv);
        st.w = f2bf(o[dm][4 * g + 3] * inv);
        *(ushort4*)(orow + 32 * dm + 8 * g + 4 * hi) = st;
      }
  }
}

// ---------------- launch ----------------
extern "C" void kernel_launch(void* const* d_in, const int* in_sizes, int n_in,
                              void* d_out, int out_size, void* d_ws, size_t ws_size,
                              hipStream_t stream) {
  const float* hs        = (const float*)d_in[0];
  const float* c_attn_w  = (const float*)d_in[1];
  const float* c_attn_b  = (const float*)d_in[2];
  const float* c_proj_w  = (const float*)d_in[3];
  const float* c_proj_b  = (const float*)d_in[4];
  float* out = (float*)d_out;

  char* ws = (char*)d_ws;
  size_t off = 0;
  u16* xb     = (u16*)(ws + off); off += (size_t)Mm * Ee * 2;
  u16* wqkvt  = (u16*)(ws + off); off += (size_t)N3 * Ee * 2;
  u16* wprojt = (u16*)(ws + off); off += (size_t)Ee * Ee * 2;
  u16* Qr     = (u16*)(ws + off); off += (size_t)64 * BHSTRIDE * 2;
  u16* Kp     = (u16*)(ws + off); off += (size_t)64 * BHSTRIDE * 2;
  u16* Vp     = (u16*)(ws + off); off += (size_t)64 * BHSTRIDE * 2;
  u16* aoutb  = (u16*)(ws + off); off += (size_t)Mm * Ee * 2;
  if (ws_size < off) return;

  (void)hipFuncSetAttribute(reinterpret_cast<const void*>(gemm256_qkv),
                            hipFuncAttributeMaxDynamicSharedMemorySize, 131072);
  (void)hipFuncSetAttribute(reinterpret_cast<const void*>(gemm_proj),
                            hipFuncAttributeMaxDynamicSharedMemorySize, 147456);

  cast_x_kernel<<<2048, 256, 0, stream>>>(hs, xb, Mm * Ee / 4);
  transpose_cast_kernel<<<dim3(N3 / 32, Ee / 32), 256, 0, stream>>>(c_attn_w, wqkvt, Ee, N3);
  transpose_cast_kernel<<<dim3(Ee / 32, Ee / 32), 256, 0, stream>>>(c_proj_w, wprojt, Ee, Ee);
  // GEMM1: 32 m-tiles x 12 n-tiles = 384 blocks, 512 threads, 128 KB LDS
  gemm256_qkv<<<384, 512, 131072, stream>>>(xb, wqkvt, c_attn_b, Qr, Kp, Vp);
  attn_kernel<<<dim3(Bb * Hh, 64), 256, 0, stream>>>(Qr, Kp, Vp, aoutb);
  // GEMM2: 64 m-tiles x 4 n-tiles = 256 blocks (exactly 1 round)
  gemm_proj<<<256, 512, 147456, stream>>>(
      aoutb, wprojt, c_proj_b, 4, 32, out);
}

// Round 19
// 156.193 us; speedup vs baseline: 1.0886x; 1.0886x over previous
//
#include <hip/hip_runtime.h>

typedef __attribute__((ext_vector_type(8))) __bf16 bf16x8;
typedef __attribute__((ext_vector_type(2))) __bf16 bf16x2;
typedef __attribute__((ext_vector_type(8))) unsigned short u16x8;
typedef __attribute__((ext_vector_type(4))) float f32x4;
typedef __attribute__((ext_vector_type(16))) float f32x16;
typedef __attribute__((ext_vector_type(2))) unsigned int u32x2;
typedef __attribute__((ext_vector_type(4))) unsigned int u32x4;
typedef unsigned short u16;
typedef unsigned int u32;

constexpr int Bb = 4, Ss = 2048, Ee = 1024, Hh = 16, HDd = 64;
constexpr int Mm = Bb * Ss;   // 8192
constexpr int N3 = 3 * Ee;    // 3072
constexpr float QSC = 0.18033688011112042f;  // 0.125 * log2(e)
constexpr int BHSTRIDE = Ss * HDd;            // 131072 u16 per (b,h) slice
constexpr float M0 = 8.0f;                    // static softmax base (exp2 units)

__device__ __forceinline__ u16 f2bf(float f) {
  u32 u = __builtin_bit_cast(u32, f);
  u = (u + 0x7FFFu + ((u >> 16) & 1u)) >> 16;
  return (u16)u;
}
__device__ __forceinline__ u32 pk2(float a, float b) {
  bf16x2 t;
  t[0] = (__bf16)a;
  t[1] = (__bf16)b;
  return __builtin_bit_cast(u32, t);
}
// raw v_exp_f32 (no denormal-fixup sequence); inputs are <= 0, -inf -> 0
__device__ __forceinline__ float ex2(float x) {
#if __has_builtin(__builtin_amdgcn_exp2f)
  return __builtin_amdgcn_exp2f(x);
#else
  float r;
  asm volatile("v_exp_f32 %0, %1" : "=v"(r) : "v"(x));
  return r;
#endif
}

__device__ __forceinline__ void gload_lds16(const void* g, void* l) {
  __builtin_amdgcn_global_load_lds(
      (__attribute__((address_space(1))) void*)g,
      (__attribute__((address_space(3))) void*)l, 16, 0, 0);
}

__device__ __forceinline__ f32x4 mfma16(bf16x8 a, bf16x8 b, f32x4 c) {
  return __builtin_amdgcn_mfma_f32_16x16x32_bf16(a, b, c, 0, 0, 0);
}
__device__ __forceinline__ f32x16 mfma32(bf16x8 a, bf16x8 b, f32x16 c) {
  return __builtin_amdgcn_mfma_f32_32x32x16_bf16(a, b, c, 0, 0, 0);
}

// ---------------- cast fp32 -> bf16 ----------------
__global__ void cast_x_kernel(const float* __restrict__ x, u16* __restrict__ xb, int n4) {
  int i = blockIdx.x * blockDim.x + threadIdx.x;
  int stride = gridDim.x * blockDim.x;
  for (; i < n4; i += stride) {
    float4 v = reinterpret_cast<const float4*>(x)[i];
    ushort4 o;
    o.x = f2bf(v.x); o.y = f2bf(v.y); o.z = f2bf(v.z); o.w = f2bf(v.w);
    reinterpret_cast<ushort4*>(xb)[i] = o;
  }
}

// ---------------- transpose-cast weight [K][N] fp32 -> [N][K] bf16 ----------------
__global__ void transpose_cast_kernel(const float* __restrict__ W, u16* __restrict__ Wt,
                                      int K, int N) {
  __shared__ float tile[32][33];
  int n0 = blockIdx.x * 32, k0 = blockIdx.y * 32;
  int tx = threadIdx.x & 31, ty = threadIdx.x >> 5;
#pragma unroll
  for (int i = 0; i < 4; ++i)
    tile[ty + i * 8][tx] = W[(size_t)(k0 + ty + i * 8) * N + n0 + tx];
  __syncthreads();
#pragma unroll
  for (int i = 0; i < 4; ++i)
    Wt[(size_t)(n0 + ty + i * 8) * K + k0 + tx] = f2bf(tile[tx][ty + i * 8]);
}

// ---------------- pipelined GEMM: 128x256, BK=64, 8 waves, 3-buf LDS --------
// Counted vmcnt (never drains mid-loop), prefetch depth 2 tiles. (R11/R15-proven,
// mfma16 inner loop — conflict-free LDS read pattern.)
template <int MODE>
__global__ __launch_bounds__(512, 1) void gemm_pipe(
    const u16* __restrict__ A, const u16* __restrict__ Bt,
    const float* __restrict__ bias, int xtiles, int cpx,
    float* __restrict__ Cout, u16* __restrict__ Qr,
    u16* __restrict__ Kp, u16* __restrict__ Vp) {
  extern __shared__ __attribute__((aligned(16))) u16 dyn[];
  constexpr int K = 1024, NT = 16;
  constexpr int BUFSTRIDE = 24576;  // u16: 48KB per buffer

  int f = blockIdx.x;
  int swz = (f & 7) * cpx + (f >> 3);  // XCD swizzle (grid % 8 == 0)
  int bx = swz % xtiles, by = swz / xtiles;
  int m0 = by * 128, n0 = bx * 256;

  int tid = threadIdx.x, lane = tid & 63, wid = tid >> 6;
  int wr = wid >> 2, wc = wid & 3;  // wave grid 2(M) x 4(N), each 64x64
  int l7 = lane & 7, l8 = lane >> 3;
  int swcol = (l7 ^ l8) * 8;  // inverse-swizzled source chunk

  const u16* Ab = A + (size_t)(m0 + l8) * K + swcol;
  const u16* Bb = Bt + (size_t)(n0 + l8) * K + swcol;

  f32x4 acc[4][4];
  const f32x4 fz = {0.f, 0.f, 0.f, 0.f};
#pragma unroll
  for (int mi = 0; mi < 4; ++mi)
#pragma unroll
    for (int nj = 0; nj < 4; ++nj) acc[mi][nj] = fz;

  auto STA = [&](int tt, int c) {
    int ch = wid * 2 + c;
    gload_lds16(Ab + (size_t)(ch * 8) * K + tt * 64,
                dyn + (tt % 3) * BUFSTRIDE + ch * 512);
  };
  auto STB = [&](int tt, int c) {
    int ch = wid * 4 + c;
    gload_lds16(Bb + (size_t)(ch * 8) * K + tt * 64,
                dyn + (tt % 3) * BUFSTRIDE + 8192 + ch * 512);
  };
  auto LDA = [&](const u16* buf, int mi, int ks) -> bf16x8 {
    int row = wr * 64 + mi * 16 + (lane & 15);
    int j = ((ks * 4 + (lane >> 4)) ^ l7) * 8;
    return *(const bf16x8*)&buf[row * 64 + j];
  };
  auto LDB = [&](const u16* buf, int ni, int ks) -> bf16x8 {
    int row = wc * 64 + ni * 16 + (lane & 15);
    int j = ((ks * 4 + (lane >> 4)) ^ l7) * 8;
    return *(const bf16x8*)&buf[row * 64 + j];
  };

#pragma unroll
  for (int c = 0; c < 2; ++c) STA(0, c);
#pragma unroll
  for (int c = 0; c < 4; ++c) STB(0, c);
#pragma unroll
  for (int c = 0; c < 2; ++c) STA(1, c);
#pragma unroll
  for (int c = 0; c < 4; ++c) STB(1, c);

  for (int t = 0; t < NT; ++t) {
    const u16* Ar = dyn + (t % 3) * BUFSTRIDE;
    const u16* Br = Ar + 8192;
    if (t + 1 < NT)
      asm volatile("s_waitcnt vmcnt(6)" ::: "memory");
    else
      asm volatile("s_waitcnt vmcnt(0)" ::: "memory");
    __builtin_amdgcn_sched_barrier(0);
    __builtin_amdgcn_s_barrier();
    __builtin_amdgcn_sched_barrier(0);

    bool pre2 = (t + 2) < NT;
#pragma unroll
    for (int kk = 0; kk < 2; ++kk) {
      bf16x8 af[4], bfr[4];
#pragma unroll
      for (int mi = 0; mi < 4; ++mi) af[mi] = LDA(Ar, mi, kk);
#pragma unroll
      for (int ni = 0; ni < 4; ++ni) bfr[ni] = LDB(Br, ni, kk);
      if (kk == 0 && pre2) { STA(t + 2, 0); STA(t + 2, 1); }
      if (kk == 1 && pre2) { STB(t + 2, 0); STB(t + 2, 1); STB(t + 2, 2); STB(t + 2, 3); }
      __builtin_amdgcn_s_setprio(1);
#pragma unroll
      for (int mi = 0; mi < 4; ++mi)
#pragma unroll
        for (int ni = 0; ni < 4; ++ni)
          acc[mi][ni] = mfma16(af[mi], bfr[ni], acc[mi][ni]);
      __builtin_amdgcn_s_setprio(0);
      asm volatile("" ::: "memory");
    }
  }
  __syncthreads();

  if (MODE == 0) {
    int Nn = xtiles * 256;
#pragma unroll
    for (int nj = 0; nj < 4; ++nj) {
      int n = n0 + wc * 64 + nj * 16 + (lane & 15);
      float bn = bias[n];
#pragma unroll
      for (int mi = 0; mi < 4; ++mi)
#pragma unroll
        for (int r = 0; r < 4; ++r) {
          int m = m0 + wr * 64 + mi * 16 + (lane >> 4) * 4 + r;
          Cout[(size_t)m * Nn + n] = acc[mi][nj][r] + bn;
        }
    }
  } else {
    int gi0 = bx * 4;
    int bb = m0 >> 11;
    int mrow0 = m0 & 2047;
#pragma unroll
    for (int p = 0; p < 2; ++p) {
      if ((wc >> 1) == p) {
        int gg = wc & 1;
        int gi = gi0 + p * 2 + gg;
        int typ = gi % 3;
        float cs = (typ == 0) ? QSC : 1.0f;
#pragma unroll
        for (int nj = 0; nj < 4; ++nj) {
          int dl = nj * 16 + (lane & 15);
          float bn = bias[gi * 64 + dl];
#pragma unroll
          for (int mi = 0; mi < 4; ++mi)
#pragma unroll
            for (int r = 0; r < 4; ++r) {
              int row = wr * 64 + mi * 16 + (lane >> 4) * 4 + r;
              dyn[(gg * 128 + row) * 72 + dl] = f2bf((acc[mi][nj][r] + bn) * cs);
            }
        }
      }
      __syncthreads();
#pragma unroll
      for (int gg = 0; gg < 2; ++gg) {
        int gi = gi0 + p * 2 + gg;
        int typ = gi % 3, h = gi / 3;
        size_t basebh = (size_t)(bb * 16 + h) * BHSTRIDE;
        if (typ == 2) {
#pragma unroll
          for (int i = 0; i < 2; ++i) {
            int c = tid + 512 * i;
            int dl = c & 63, s64 = (c >> 6) & 1, kv8 = c >> 7;
            u16x8 val;
            int lrow = gg * 128 + s64 * 64 + kv8 * 8;
#pragma unroll
            for (int e = 0; e < 8; ++e) val[e] = dyn[(lrow + e) * 72 + dl];
            int tile = (mrow0 >> 6) + s64;
            size_t o = basebh + (size_t)tile * 4096 + (dl >> 5) * 2048 +
                       (kv8 >> 1) * 512 + (kv8 & 1) * 256 + (dl & 31) * 8;
            *(u16x8*)(Vp + o) = val;
          }
        } else {
#pragma unroll
          for (int i = 0; i < 2; ++i) {
            int c = tid + 512 * i;
            int sl = c >> 3, dc = c & 7;
            u16x8 val = *(const u16x8*)&dyn[(gg * 128 + sl) * 72 + dc * 8];
            int srw = mrow0 + sl;
            if (typ == 0) {
              *(u16x8*)(Qr + basebh + (size_t)srw * 64 + dc * 8) = val;
            } else {
              int tile = srw >> 6, rl = srw & 63;
              size_t o = basebh + (size_t)tile * 4096 + (rl >> 5) * 2048 +
                         (dc >> 1) * 512 + (dc & 1) * 256 + (rl & 31) * 8;
              *(u16x8*)(Kp + o) = val;
            }
          }
        }
      }
      __syncthreads();
    }
  }
}

// ---------------- causal flash attention: 4-wave KV-split, static base ------
// (exact R15 kernel: raw exp2, -M0 in accumulator, permlane exchange)
__global__ __launch_bounds__(256) void attn_kernel(const u16* __restrict__ Qr,
                                                   const u16* __restrict__ Kp,
                                                   const u16* __restrict__ Vp,
                                                   u16* __restrict__ aout) {
  __shared__ float mbuf[2][64][33];  // [slot][lane][{l, o[32]}]

  int bh = blockIdx.x;
  int j = gridDim.y - 1 - blockIdx.y;  // q-block 0..63, big-first
  int tid = threadIdx.x, w = tid >> 6, lane = tid & 63;
  int hi = lane >> 5, ln31 = lane & 31;
  int qrow = 32 * j + ln31;
  int nt = (j >> 1) + 1;
  int par = (j & 1) ? 32 : 0;

  size_t basebh = (size_t)bh * BHSTRIDE;
  const u16* kpb = Kp + basebh + hi * 256 + ln31 * 8;
  const u16* vpb = Vp + basebh + hi * 256 + ln31 * 8;

  bf16x8 qf[4];
#pragma unroll
  for (int kc = 0; kc < 4; ++kc)
    qf[kc] = *(const bf16x8*)(Qr + basebh + (size_t)qrow * 64 + kc * 16 + hi * 8);

  f32x16 o[2];
#pragma unroll
  for (int dm = 0; dm < 2; ++dm)
#pragma unroll
    for (int e = 0; e < 16; ++e) o[dm][e] = 0.f;
  float lrun = 0.f;

  for (int t = w; t < nt; t += 4) {
    const u16* kpt = kpb + (size_t)t * 4096;
    const u16* vpt = vpb + (size_t)t * 4096;
    bf16x8 kf[2][4], vf[2][4];
#pragma unroll
    for (int mt = 0; mt < 2; ++mt)
#pragma unroll
      for (int kc = 0; kc < 4; ++kc)
        kf[mt][kc] = *(const bf16x8*)(kpt + mt * 2048 + kc * 512);
#pragma unroll
    for (int dm = 0; dm < 2; ++dm)
#pragma unroll
      for (int kw = 0; kw < 4; ++kw)
        vf[dm][kw] = *(const bf16x8*)(vpt + dm * 2048 + kw * 512);

    f32x16 sc[2];
#pragma unroll
    for (int mt = 0; mt < 2; ++mt)
#pragma unroll
      for (int e = 0; e < 16; ++e) sc[mt][e] = -M0;
    __builtin_amdgcn_s_setprio(1);
#pragma unroll
    for (int mt = 0; mt < 2; ++mt)
#pragma unroll
      for (int kc = 0; kc < 4; ++kc)
        sc[mt] = mfma32(kf[mt][kc], qf[kc], sc[mt]);
    __builtin_amdgcn_s_setprio(0);

    if (t == nt - 1) {
#pragma unroll
      for (int mt = 0; mt < 2; ++mt)
#pragma unroll
        for (int r = 0; r < 16; ++r) {
          bool msk = (32 * mt + (r & 3) + 8 * (r >> 2) + 4 * hi) > (ln31 + par);
          sc[mt][r] = msk ? -__builtin_inff() : sc[mt][r];
        }
    }
    float s0a = 0.f, s1a = 0.f, s2a = 0.f, s3a = 0.f;
#pragma unroll
    for (int mt = 0; mt < 2; ++mt)
#pragma unroll
      for (int r = 0; r < 16; ++r) {
        float e = ex2(sc[mt][r]);
        sc[mt][r] = e;
        if ((r & 3) == 0) s0a += e;
        else if ((r & 3) == 1) s1a += e;
        else if ((r & 3) == 2) s2a += e;
        else s3a += e;
      }
    float sum = (s0a + s1a) + (s2a + s3a);
    sum += __shfl_xor(sum, 32);
    lrun += sum;

#pragma unroll
    for (int kw = 0; kw < 4; ++kw) {
      int mt = kw >> 1, k8 = (kw & 1) * 8;
      u32 a0 = pk2(sc[mt][k8 + 0], sc[mt][k8 + 1]);
      u32 a1 = pk2(sc[mt][k8 + 2], sc[mt][k8 + 3]);
      u32 b0 = pk2(sc[mt][k8 + 4], sc[mt][k8 + 5]);
      u32 b1 = pk2(sc[mt][k8 + 6], sc[mt][k8 + 7]);
      u32x2 r0 = __builtin_amdgcn_permlane32_swap(a0, b0, false, false);
      u32x2 r1 = __builtin_amdgcn_permlane32_swap(a1, b1, false, false);
      u32x4 fw;
      fw.x = r0.x;
      fw.y = r1.x;
      fw.z = r0.y;
      fw.w = r1.y;
      bf16x8 pf = __builtin_bit_cast(bf16x8, fw);
      __builtin_amdgcn_s_setprio(1);
#pragma unroll
      for (int dm = 0; dm < 2; ++dm)
        o[dm] = mfma32(vf[dm][kw], pf, o[dm]);  // O^T[d][q]
      __builtin_amdgcn_s_setprio(0);
    }
  }

  // ---- merge partials: plain sums (same static base) ----
  if (w >= 2) {
    mbuf[w - 2][lane][0] = lrun;
#pragma unroll
    for (int dm = 0; dm < 2; ++dm)
#pragma unroll
      for (int e = 0; e < 16; ++e) mbuf[w - 2][lane][1 + dm * 16 + e] = o[dm][e];
  }
  __syncthreads();
  if (w < 2) {
    lrun += mbuf[w][lane][0];
#pragma unroll
    for (int dm = 0; dm < 2; ++dm)
#pragma unroll
      for (int e = 0; e < 16; ++e) o[dm][e] += mbuf[w][lane][1 + dm * 16 + e];
  }
  __syncthreads();
  if (w == 1) {
    mbuf[0][lane][0] = lrun;
#pragma unroll
    for (int dm = 0; dm < 2; ++dm)
#pragma unroll
      for (int e = 0; e < 16; ++e) mbuf[0][lane][1 + dm * 16 + e] = o[dm][e];
  }
  __syncthreads();
  if (w == 0) {
    lrun += mbuf[0][lane][0];
#pragma unroll
    for (int dm = 0; dm < 2; ++dm)
#pragma unroll
      for (int e = 0; e < 16; ++e) o[dm][e] += mbuf[0][lane][1 + dm * 16 + e];
    int b = bh >> 4, h = bh & 15;
    float inv = 1.f / lrun;
    u16* orow = aout + (size_t)(b * Ss + qrow) * Ee + h * HDd;
#pragma unroll
    for (int dm = 0; dm < 2; ++dm)
#pragma unroll
      for (int g = 0; g < 4; ++g) {
        ushort4 st;
        st.x = f2bf(o[dm][4 * g + 0] * inv);
        st.y = f2bf(o[dm][4 * g + 1] * inv);
        st.z = f2bf(o[dm][4 * g + 2] * inv);
        st.w = f2bf(o[dm][4 * g + 3] * inv);
        *(ushort4*)(orow + 32 * dm + 8 * g + 4 * hi) = st;
      }
  }
}

// ---------------- launch ----------------
extern "C" void kernel_launch(void* const* d_in, const int* in_sizes, int n_in,
                              void* d_out, int out_size, void* d_ws, size_t ws_size,
                              hipStream_t stream) {
  const float* hs        = (const float*)d_in[0];
  const float* c_attn_w  = (const float*)d_in[1];
  const float* c_attn_b  = (const float*)d_in[2];
  const float* c_proj_w  = (const float*)d_in[3];
  const float* c_proj_b  = (const float*)d_in[4];
  float* out = (float*)d_out;

  char* ws = (char*)d_ws;
  size_t off = 0;
  u16* xb     = (u16*)(ws + off); off += (size_t)Mm * Ee * 2;
  u16* wqkvt  = (u16*)(ws + off); off += (size_t)N3 * Ee * 2;
  u16* wprojt = (u16*)(ws + off); off += (size_t)Ee * Ee * 2;
  u16* Qr     = (u16*)(ws + off); off += (size_t)64 * BHSTRIDE * 2;
  u16* Kp     = (u16*)(ws + off); off += (size_t)64 * BHSTRIDE * 2;
  u16* Vp     = (u16*)(ws + off); off += (size_t)64 * BHSTRIDE * 2;
  u16* aoutb  = (u16*)(ws + off); off += (size_t)Mm * Ee * 2;
  if (ws_size < off) return;

  (void)hipFuncSetAttribute(reinterpret_cast<const void*>(gemm_pipe<1>),
                            hipFuncAttributeMaxDynamicSharedMemorySize, 147456);
  (void)hipFuncSetAttribute(reinterpret_cast<const void*>(gemm_pipe<0>),
                            hipFuncAttributeMaxDynamicSharedMemorySize, 147456);

  cast_x_kernel<<<2048, 256, 0, stream>>>(hs, xb, Mm * Ee / 4);
  transpose_cast_kernel<<<dim3(N3 / 32, Ee / 32), 256, 0, stream>>>(c_attn_w, wqkvt, Ee, N3);
  transpose_cast_kernel<<<dim3(Ee / 32, Ee / 32), 256, 0, stream>>>(c_proj_w, wprojt, Ee, Ee);
  gemm_pipe<1><<<768, 512, 147456, stream>>>(
      xb, wqkvt, c_attn_b, 12, 96, nullptr, Qr, Kp, Vp);
  attn_kernel<<<dim3(Bb * Hh, 64), 256, 0, stream>>>(Qr, Kp, Vp, aoutb);
  gemm_pipe<0><<<256, 512, 147456, stream>>>(
      aoutb, wprojt, c_proj_b, 4, 32, out, nullptr, nullptr, nullptr);
}